// Round 25
// baseline (245.626 us; speedup 1.0000x reference)
//
#include <hip/hip_runtime.h>
#include <hip/hip_bf16.h>

typedef __bf16 bf16_t;
typedef __attribute__((ext_vector_type(8))) __bf16 bf16x8;
typedef __attribute__((ext_vector_type(4))) __bf16 bf16x4;
typedef __attribute__((ext_vector_type(4))) float f32x4;
typedef __attribute__((ext_vector_type(16))) float f32x16;

#define DEV __device__ __forceinline__
#define LOG2E 1.44269504088896f

DEV void gload16(const bf16_t* g, void* l) {
  __builtin_amdgcn_global_load_lds((const __attribute__((address_space(1))) void*)g,
                                   (__attribute__((address_space(3))) void*)l, 16, 0, 0);
}

DEV f32x4 mfma16(bf16x8 a, bf16x8 b, f32x4 c) {
  return __builtin_amdgcn_mfma_f32_16x16x32_bf16(a, b, c, 0, 0, 0);
}
DEV f32x16 mfma32(bf16x8 a, bf16x8 b, f32x16 c) {
  return __builtin_amdgcn_mfma_f32_32x32x16_bf16(a, b, c, 0, 0, 0);
}

// raw v_exp_f32 (2^x) — inputs bounded |x|<~4, no denormal fixup needed
DEV float fexp2(float x) {
#if __has_builtin(__builtin_amdgcn_exp2f)
  return __builtin_amdgcn_exp2f(x);
#else
  float r;
  asm("v_exp_f32 %0, %1" : "=v"(r) : "v"(x));
  return r;
#endif
}

DEV bf16x8 cvt8(const float* p0, const float* p1) {
  bf16x8 v;
  v[0] = (bf16_t)p0[0]; v[1] = (bf16_t)p0[1]; v[2] = (bf16_t)p0[2]; v[3] = (bf16_t)p0[3];
  v[4] = (bf16_t)p1[0]; v[5] = (bf16_t)p1[1]; v[6] = (bf16_t)p1[2]; v[7] = (bf16_t)p1[3];
  return v;
}

DEV unsigned pk2(float lo, float hi) {
  union { bf16_t h[2]; unsigned u; } x;
  x.h[0] = (bf16_t)lo; x.h[1] = (bf16_t)hi;
  return x.u;
}

DEV bf16x8 lds_read_swz7(const bf16_t* base, int row, int kByte) {   // 128B rows, 8-slot swz
  int off = (row << 7) + (kByte ^ ((row & 7) << 4));
  return *(const bf16x8*)((const char*)base + off);
}
DEV bf16x8 lds_read_swz8b(const bf16_t* base, int row, int kByte) {  // 256B rows, 16-slot swz
  int off = (row << 8) + (kByte ^ ((row & 15) << 4));
  return *(const bf16x8*)((const char*)base + off);
}

// ---------------- k_prep: qkv (blocks 0..1023) + weight conversion (1024..3327) ----------------
DEV void wconv_tile(bf16_t* pool, const float* in, bf16_t* out, int R, int C, int tile) {
  bf16_t (*Ts)[72] = (bf16_t(*)[72])pool;  // 64x72
  int tilesC = C >> 6;
  int tr = tile / tilesC, tc = tile % tilesC;
  int t = threadIdx.x;
  int rr = t >> 3, c0 = (t & 7) << 3;
#pragma unroll
  for (int i = 0; i < 2; ++i) {
    int row = rr + i * 32;
    const float* src = in + (size_t)(tr * 64 + row) * C + tc * 64 + c0;
    float4 a = *(const float4*)src;
    float4 b = *(const float4*)(src + 4);
    *(bf16x8*)&Ts[row][c0] = cvt8(&a.x, &b.x);
  }
  __syncthreads();
#pragma unroll
  for (int i = 0; i < 2; ++i) {
    int nl = rr + i * 32;
    bf16x8 v;
#pragma unroll
    for (int j = 0; j < 8; ++j) v[j] = Ts[c0 + j][nl];
    *(bf16x8*)(out + (size_t)(tc * 64 + nl) * R + tr * 64 + c0) = v;
  }
}

DEV void qkv_body(bf16_t* pool, int b, const float* value,
    const float* Wq, const float* Wk, const float* Wv,
    bf16_t* Q, bf16_t* K, bf16_t* VT) {
  bf16_t* Xs = pool;              // 128*72
  bf16_t* Wt = pool + 128 * 72;   // 3 x 64*72
  int cn = b & 15, h = (b >> 4) & 15, n = (b >> 8) & 1, s = b >> 9;
  int t = threadIdx.x, lane = t & 63, w = t >> 6;
  int lg = (lane >> 4) & 3, ll = lane & 15;
  int hbase = (s * 2 + n) * 16 + h;
  const float* xbase = value + (size_t)(((n * 16 + cn) * 2 + s) * 128) * 1024 + h * 64;
#pragma unroll
  for (int i = 0; i < 4; ++i) {
    int c = t + i * 256;
    int row = c >> 3, d0 = (c & 7) << 3;
    const float* src = xbase + (size_t)row * 1024 + d0;
    float4 a = *(const float4*)src;
    float4 b2 = *(const float4*)(src + 4);
    *(bf16x8*)&Xs[row * 72 + d0] = cvt8(&a.x, &b2.x);
  }
  const float* Wm[3] = {Wq, Wk, Wv};
#pragma unroll
  for (int m = 0; m < 3; ++m) {
    float sc = (m == 0) ? (0.03125f * LOG2E) : 1.0f;
    for (int i = 0; i < 16; ++i) {
      int f = t * 16 + i;
      int k = f >> 6, col = f & 63;
      Wt[m * 64 * 72 + col * 72 + k] = (bf16_t)(Wm[m][f] * sc);
    }
  }
  __syncthreads();
  f32x4 acc[3][2][4] = {};
#pragma unroll
  for (int kc = 0; kc < 2; ++kc) {
    bf16x8 a[2];
#pragma unroll
    for (int rt = 0; rt < 2; ++rt)
      a[rt] = *(const bf16x8*)&Xs[(w * 32 + rt * 16 + ll) * 72 + kc * 32 + lg * 8];
#pragma unroll
    for (int m = 0; m < 3; ++m)
#pragma unroll
      for (int ct = 0; ct < 4; ++ct) {
        bf16x8 bf = *(const bf16x8*)&Wt[m * 64 * 72 + (ct * 16 + ll) * 72 + kc * 32 + lg * 8];
#pragma unroll
        for (int rt = 0; rt < 2; ++rt)
          acc[m][rt][ct] = mfma16(a[rt], bf, acc[m][rt][ct]);
      }
  }
  bf16_t* outp[2] = {Q, K};
  size_t obase = ((size_t)hbase * 2048 + cn * 128) * 64;
#pragma unroll
  for (int m = 0; m < 2; ++m)
#pragma unroll
    for (int rt = 0; rt < 2; ++rt)
#pragma unroll
      for (int ct = 0; ct < 4; ++ct)
#pragma unroll
        for (int r = 0; r < 4; ++r) {
          int lrow = w * 32 + rt * 16 + lg * 4 + r;
          int d = ct * 16 + ll;
          outp[m][obase + (size_t)lrow * 64 + d] = (bf16_t)acc[m][rt][ct][r];
        }
  __syncthreads();
  bf16_t* XsT = Xs;  // [64][136]
#pragma unroll
  for (int rt = 0; rt < 2; ++rt)
#pragma unroll
    for (int ct = 0; ct < 4; ++ct)
#pragma unroll
      for (int r = 0; r < 4; ++r) {
        int lrow = w * 32 + rt * 16 + lg * 4 + r;
        int d = ct * 16 + ll;
        XsT[d * 136 + lrow] = (bf16_t)acc[2][rt][ct][r];
      }
  __syncthreads();
#pragma unroll
  for (int p = 0; p < 4; ++p) {
    int d = p * 16 + (t >> 4);
    int l0 = (t & 15) * 8;
    bf16x8 v;
#pragma unroll
    for (int j = 0; j < 8; ++j) {
      int pos = l0 + j;
      int key = (pos & ~12) | ((pos & 4) << 1) | ((pos & 8) >> 1);  // swap bits 2,3
      v[j] = XsT[d * 136 + key];
    }
    *(bf16x8*)(VT + ((size_t)hbase * 64 + d) * 2048 + cn * 128 + l0) = v;
  }
}

__global__ __launch_bounds__(256) void k_prep(const float* __restrict__ value,
    const float* __restrict__ Wq, const float* __restrict__ Wk, const float* __restrict__ Wv,
    bf16_t* __restrict__ Q, bf16_t* __restrict__ K, bf16_t* __restrict__ VT,
    const float* __restrict__ Wo, const float* __restrict__ W1, const float* __restrict__ W2,
    bf16_t* __restrict__ WoT, bf16_t* __restrict__ W1T, bf16_t* __restrict__ W2T) {
  __shared__ alignas(16) bf16_t pool[128 * 72 + 3 * 64 * 72];  // 45 KB
  int b = blockIdx.x;
  if (b < 1024) {
    qkv_body(pool, b, value, Wq, Wk, Wv, Q, K, VT);
  } else {
    int tile = b - 1024;
    if (tile < 256) wconv_tile(pool, Wo, WoT, 1024, 1024, tile);
    else if (tile < 1280) wconv_tile(pool, W1, W1T, 1024, 4096, tile - 256);
    else wconv_tile(pool, W2, W2T, 4096, 1024, tile - 1280);
  }
}

// ---------------- flash attention (r22 proven: 8-wave, launch_bounds(512,2)) ----------------
__global__ __launch_bounds__(512, 2) void k_flash(const bf16_t* __restrict__ Qg,
    const bf16_t* __restrict__ Kg, const bf16_t* __restrict__ VTg, bf16_t* __restrict__ AO) {
  __shared__ alignas(16) bf16_t Ks[2][128 * 64];
  __shared__ alignas(16) bf16_t Vt[2][64 * 128];
  int b0 = blockIdx.x;
  int b = (b0 & 7) * 64 + (b0 >> 3);  // T1 chunked XCD swizzle (nwg=512)
  int qt = b & 7, h = (b >> 3) & 15, n = (b >> 7) & 1, s = b >> 8;
  int t = threadIdx.x, lane = t & 63, w = t >> 6;  // w in 0..7
  int l31 = lane & 31, hi = lane >> 5;
  size_t hoff = ((size_t)((s * 2 + n) * 16 + h)) << 17;
  const bf16_t* Qh = Qg + hoff;
  const bf16_t* Kh = Kg + hoff;
  const bf16_t* VTh = VTg + hoff;
  int qrow = qt * 256 + w * 32 + l31;
  bf16x8 qf[4];
#pragma unroll
  for (int kc4 = 0; kc4 < 4; ++kc4)
    qf[kc4] = *(const bf16x8*)(Qh + (size_t)qrow * 64 + kc4 * 16 + hi * 8);
  f32x16 oacc[2], lacc, zro;
#pragma unroll
  for (int r = 0; r < 16; ++r) {
    oacc[0][r] = 0.f; oacc[1][r] = 0.f; lacc[r] = 0.f; zro[r] = 0.f;
  }
  bf16x8 ones;
#pragma unroll
  for (int j = 0; j < 8; ++j) ones[j] = (bf16_t)1.0f;

  int l8s = (((lane & 7) ^ (lane >> 3)) << 3);
  const bf16_t* kbase = Kh + (size_t)(w * 16 + (lane >> 3)) * 64 + l8s;
  const bf16_t* vbase[2];
#pragma unroll
  for (int i = 0; i < 2; ++i) {
    int row = w * 8 + i * 4 + (lane >> 4);
    vbase[i] = VTh + (size_t)row * 2048 + (((lane & 15) ^ (row & 15)) << 3);
  }
  auto stage = [&](int buf, int kt0) {
    int koff = kt0 * 8192;
    int voff = kt0 * 128;
#pragma unroll
    for (int i = 0; i < 2; ++i)
      gload16(kbase + koff + i * 512, (char*)Ks[buf] + (w * 2 + i) * 1024);
#pragma unroll
    for (int i = 0; i < 2; ++i)
      gload16(vbase[i] + voff, (char*)Vt[buf] + (w * 2 + i) * 1024);
  };

  stage(0, 0);
  __syncthreads();
  for (int kt0 = 0; kt0 < 16; ++kt0) {
    int cur = kt0 & 1;
    if (kt0 < 15) stage(cur ^ 1, kt0 + 1);
    f32x16 sacc[4];
    __builtin_amdgcn_s_setprio(1);
#pragma unroll
    for (int kb = 0; kb < 4; ++kb) {
      bf16x8 kf = lds_read_swz7(Ks[cur], kb * 32 + l31, hi * 16);
      sacc[kb] = mfma32(kf, qf[0], zro);
#pragma unroll
      for (int kc4 = 1; kc4 < 4; ++kc4) {
        kf = lds_read_swz7(Ks[cur], kb * 32 + l31, kc4 * 32 + hi * 16);
        sacc[kb] = mfma32(kf, qf[kc4], sacc[kb]);
      }
    }
    __builtin_amdgcn_s_setprio(0);
#pragma unroll
    for (int kb = 0; kb < 4; ++kb) {
#pragma unroll
      for (int r = 0; r < 16; ++r)
        sacc[kb][r] = fexp2(sacc[kb][r]);
      __builtin_amdgcn_s_setprio(1);
#pragma unroll
      for (int c = 0; c < 2; ++c) {
        int base = 8 * c;
        union { unsigned u[4]; bf16x8 v; } pb;
#pragma unroll
        for (int jj = 0; jj < 4; ++jj)
          pb.u[jj] = pk2(sacc[kb][base + 2 * jj], sacc[kb][base + 2 * jj + 1]);
        int kc16 = kb * 2 + c;
        lacc = mfma32(ones, pb.v, lacc);
#pragma unroll
        for (int dblk = 0; dblk < 2; ++dblk) {
          bf16x8 vf = lds_read_swz8b(Vt[cur], dblk * 32 + l31, kc16 * 32 + hi * 16);
          oacc[dblk] = mfma32(vf, pb.v, oacc[dblk]);
        }
      }
      __builtin_amdgcn_s_setprio(0);
    }
    __syncthreads();
  }
  float lrun = lacc[0];
  bf16_t* AOs = AO + ((size_t)s) * 4194304;
  float rl = 1.f / lrun;
  size_t rowbase = ((size_t)(n * 2048 + qrow)) * 1024 + h * 64;
#pragma unroll
  for (int dblk = 0; dblk < 2; ++dblk)
#pragma unroll
    for (int rp = 0; rp < 4; ++rp) {
      bf16x4 ov;
#pragma unroll
      for (int rq = 0; rq < 4; ++rq) ov[rq] = (bf16_t)(oacc[dblk][rp * 4 + rq] * rl);
      int d0 = dblk * 32 + rp * 8 + hi * 4;
      *(bf16x4*)(AOs + rowbase + d0) = ov;
    }
}

// ---------------- GEMM 128x128 (4-wave): EPI 5 fused instance-sum, f32 out ----------------
template <int EPI>
__global__ __launch_bounds__(256) void k_gemm(const bf16_t* __restrict__ A,
    const bf16_t* __restrict__ BT, void* __restrict__ outp,
    const float* __restrict__ bias, const void* __restrict__ add,
    int M, int N, int K, const bf16_t* __restrict__ A2) {
  __shared__ alignas(16) bf16_t As[128 * 64];
  __shared__ alignas(16) bf16_t Bs[128 * 64];
  int ntn = N >> 7;
  int nwg = gridDim.x;
  int b0 = blockIdx.x;
  int cpx = nwg >> 3;
  int b = (b0 & 7) * cpx + (b0 >> 3);  // chunked XCD swizzle (nwg % 8 == 0)
  int bm = b / ntn, bn = b % ntn;
  int t = threadIdx.x, lane = t & 63, w = t >> 6;
  int wr = w >> 1, wc = w & 1;
  int lg = (lane >> 4) & 3, ll = lane & 15;
  f32x4 acc[4][4] = {};
  int rA = bm * 128, rB = bn * 128;
  int l8s = (((lane & 7) ^ (lane >> 3)) << 3);
  for (int kt = 0; kt < K; kt += 64) {
#pragma unroll
    for (int i = 0; i < 4; ++i) {
      int kb = w * 4 + i;
      int row = kb * 8 + (lane >> 3);
      size_t off = (size_t)(rA + row) * K + kt + l8s;
      if (EPI == 5) {
        bf16x8 a1 = *(const bf16x8*)(A + off);
        bf16x8 a2 = *(const bf16x8*)(A2 + off);
        bf16x8 sv;
#pragma unroll
        for (int j = 0; j < 8; ++j) sv[j] = (bf16_t)((float)a1[j] + (float)a2[j]);
        *(bf16x8*)((char*)As + kb * 1024 + lane * 16) = sv;
      } else {
        gload16(A + off, (char*)As + kb * 1024);
      }
      gload16(BT + (size_t)(rB + row) * K + kt + l8s, (char*)Bs + kb * 1024);
    }
    __syncthreads();
#pragma unroll
    for (int kc = 0; kc < 2; ++kc) {
      bf16x8 a[4], bb[4];
#pragma unroll
      for (int m = 0; m < 4; ++m)
        a[m] = lds_read_swz7(As, wr * 64 + m * 16 + ll, kc * 64 + lg * 16);
#pragma unroll
      for (int nn = 0; nn < 4; ++nn)
        bb[nn] = lds_read_swz7(Bs, wc * 64 + nn * 16 + ll, kc * 64 + lg * 16);
#pragma unroll
      for (int m = 0; m < 4; ++m)
#pragma unroll
        for (int nn = 0; nn < 4; ++nn)
          acc[m][nn] = mfma16(a[m], bb[nn], acc[m][nn]);
    }
    __syncthreads();
  }
#pragma unroll
  for (int m = 0; m < 4; ++m)
#pragma unroll
    for (int nn = 0; nn < 4; ++nn)
#pragma unroll
      for (int r = 0; r < 4; ++r) {
        int row = bm * 128 + wr * 64 + m * 16 + lg * 4 + r;
        int col = bn * 128 + wc * 64 + nn * 16 + ll;
        ((float*)outp)[(size_t)row * N + col] = acc[m][nn][r];
      }
}

// ---------------- GEMM 256x128 (8-wave, launch_bounds(512,2)) ----------------
// EPI 1: bf16 out = relu(acc+bias); EPI 3: split-K raw partials (ks=0->outp, ks=1->add)
template <int EPI>
__global__ __launch_bounds__(512, 2) void k_gemm2(const bf16_t* __restrict__ A,
    const bf16_t* __restrict__ BT, void* __restrict__ outp,
    const float* __restrict__ bias, void* __restrict__ add, int M, int N, int K) {
  __shared__ alignas(16) bf16_t As[256 * 64];  // 32 KB, 32 chunks
  __shared__ alignas(16) bf16_t Bs[128 * 64];  // 16 KB, 16 chunks
  int ntn = N >> 7;
  int nwg = gridDim.x;
  int b0 = blockIdx.x;
  int cpx = nwg >> 3;
  int b = (b0 & 7) * cpx + (b0 >> 3);  // chunked XCD swizzle
  int ks = 0, k0 = 0, kend = K;
  if (EPI == 3) {
    int half = nwg >> 1;
    ks = (b >= half) ? 1 : 0;
    b -= ks * half;
    int kh = K >> 1;
    k0 = ks * kh;
    kend = k0 + kh;
  }
  int bm = b / ntn, bn = b % ntn;
  int t = threadIdx.x, lane = t & 63, w = t >> 6;  // w in 0..7
  int wr = w >> 1, wc = w & 1;                      // 4x2 wave grid
  int lg = (lane >> 4) & 3, ll = lane & 15;
  f32x4 acc[4][4] = {};
  int rA = bm * 256, rB = bn * 128;
  int l8s = (((lane & 7) ^ (lane >> 3)) << 3);
  for (int kt = k0; kt < kend; kt += 64) {
#pragma unroll
    for (int i = 0; i < 4; ++i) {  // A: 32 chunks, 4 per wave
      int kb = w * 4 + i;
      int row = kb * 8 + (lane >> 3);
      gload16(A + (size_t)(rA + row) * K + kt + l8s, (char*)As + kb * 1024);
    }
#pragma unroll
    for (int i = 0; i < 2; ++i) {  // B: 16 chunks, 2 per wave
      int kb = w * 2 + i;
      int row = kb * 8 + (lane >> 3);
      gload16(BT + (size_t)(rB + row) * K + kt + l8s, (char*)Bs + kb * 1024);
    }
    __syncthreads();
#pragma unroll
    for (int kc = 0; kc < 2; ++kc) {
      bf16x8 a[4], bb[4];
#pragma unroll
      for (int m = 0; m < 4; ++m)
        a[m] = lds_read_swz7(As, wr * 64 + m * 16 + ll, kc * 64 + lg * 16);
#pragma unroll
      for (int nn = 0; nn < 4; ++nn)
        bb[nn] = lds_read_swz7(Bs, wc * 64 + nn * 16 + ll, kc * 64 + lg * 16);
#pragma unroll
      for (int m = 0; m < 4; ++m)
#pragma unroll
        for (int nn = 0; nn < 4; ++nn)
          acc[m][nn] = mfma16(a[m], bb[nn], acc[m][nn]);
    }
    __syncthreads();
  }
#pragma unroll
  for (int m = 0; m < 4; ++m)
#pragma unroll
    for (int nn = 0; nn < 4; ++nn)
#pragma unroll
      for (int r = 0; r < 4; ++r) {
        int row = bm * 256 + wr * 64 + m * 16 + lg * 4 + r;
        int col = bn * 128 + wc * 64 + nn * 16 + ll;
        float v = acc[m][nn][r];
        size_t idx = (size_t)row * N + col;
        if (EPI == 1) {
          v += bias[col];
          ((bf16_t*)outp)[idx] = (bf16_t)fmaxf(v, 0.f);
        } else {
          float* dst = ks ? (float*)add : (float*)outp;
          dst[idx] = v;
        }
      }
}

// ---------------- LayerNorm over 1024 cols ----------------
// MODE 2: v = T+T2+bias2+add2, write xf only (final f32 out)
// MODE 4: v = T+2*bias2+add2, write xf + xb (post-attention LN, single partial)
template <int MODE>
__global__ __launch_bounds__(256) void k_ln(const float* __restrict__ T,
    const float* __restrict__ g, const float* __restrict__ b,
    float* __restrict__ xf, bf16_t* __restrict__ xb,
    const float* __restrict__ T2, const float* __restrict__ bias2,
    const float* __restrict__ add2) {
  int row = blockIdx.x, t = threadIdx.x;
  float4 v = ((const float4*)(T + (size_t)row * 1024))[t];
  {
    const float4 vb = ((const float4*)bias2)[t];
    const float4 va = ((const float4*)(add2 + (size_t)row * 1024))[t];
    float bs = (MODE == 4) ? 2.f : 1.f;
    if (MODE != 4) {
      const float4 v2 = ((const float4*)(T2 + (size_t)row * 1024))[t];
      v.x += v2.x; v.y += v2.y; v.z += v2.z; v.w += v2.w;
    }
    v.x += bs * vb.x + va.x;
    v.y += bs * vb.y + va.y;
    v.z += bs * vb.z + va.z;
    v.w += bs * vb.w + va.w;
  }
  float s1 = v.x + v.y + v.z + v.w;
  float s2 = v.x * v.x + v.y * v.y + v.z * v.z + v.w * v.w;
#pragma unroll
  for (int off = 1; off < 64; off <<= 1) {
    s1 += __shfl_xor(s1, off);
    s2 += __shfl_xor(s2, off);
  }
  __shared__ float red[8];
  int w = t >> 6, lane = t & 63;
  if (lane == 0) { red[w] = s1; red[w + 4] = s2; }
  __syncthreads();
  s1 = red[0] + red[1] + red[2] + red[3];
  s2 = red[4] + red[5] + red[6] + red[7];
  float mean = s1 * (1.f / 1024.f);
  float var = s2 * (1.f / 1024.f) - mean * mean;
  float rstd = rsqrtf(var + 1e-5f);
  const float4 gv = ((const float4*)g)[t];
  const float4 bv = ((const float4*)b)[t];
  float4 o;
  o.x = (v.x - mean) * rstd * gv.x + bv.x;
  o.y = (v.y - mean) * rstd * gv.y + bv.y;
  o.z = (v.z - mean) * rstd * gv.z + bv.z;
  o.w = (v.w - mean) * rstd * gv.w + bv.w;
  ((float4*)(xf + (size_t)row * 1024))[t] = o;
  if (MODE == 4) {
    bf16x4 ob;
    ob[0] = (bf16_t)o.x; ob[1] = (bf16_t)o.y; ob[2] = (bf16_t)o.z; ob[3] = (bf16_t)o.w;
    *(bf16x4*)(xb + (size_t)row * 1024 + t * 4) = ob;
  }
}

extern "C" void kernel_launch(void* const* d_in, const int* in_sizes, int n_in,
                              void* d_out, int out_size, void* d_ws, size_t ws_size,
                              hipStream_t stream) {
  const float* value = (const float*)d_in[0];
  const float* query = (const float*)d_in[2];
  const float* Wv = (const float*)d_in[5];
  const float* Wk = (const float*)d_in[6];
  const float* Wq = (const float*)d_in[7];
  const float* Wo = (const float*)d_in[8];
  const float* bo = (const float*)d_in[9];
  const float* g1 = (const float*)d_in[10];
  const float* b1 = (const float*)d_in[11];
  const float* W1 = (const float*)d_in[12];
  const float* bf1 = (const float*)d_in[13];
  const float* W2 = (const float*)d_in[14];
  const float* bf2 = (const float*)d_in[15];
  const float* g3 = (const float*)d_in[16];
  const float* b3 = (const float*)d_in[17];

  char* ws = (char*)d_ws;
  // race-free lifetime-planned layout, peak 0x6200000 = 98 MiB
  bf16_t* Qb    = (bf16_t*)(ws + 0x0000000);  // 16M, dead after flash
  bf16_t* Kb    = (bf16_t*)(ws + 0x1000000);  // 16M, dead after flash
  bf16_t* VTb   = (bf16_t*)(ws + 0x2000000);  // 16M, dead after flash
  bf16_t* AO    = (bf16_t*)(ws + 0x3000000);  // 16M (2x8M), dead after gemmWo
  float*  Pg0   = (float*) (ws + 0x0000000);  // 16M (over dead Qb), dead after ln4
  float*  Xf    = (float*) (ws + 0x2000000);  // 16M (over dead VTb), live to end
  bf16_t* Xb    = (bf16_t*)(ws + 0x4000000);  // 8M  (fresh), dead after gemm1
  bf16_t* Hb    = (bf16_t*)(ws + 0x0000000);  // 32M (over dead Pg0 + Kb), dead after gemmFFN2
  float*  Psk0  = (float*) (ws + 0x3000000);  // 16M (over dead AO)
  float*  Psk1  = (float*) (ws + 0x4000000);  // 16M (over dead Xb)
  bf16_t* WoT   = (bf16_t*)(ws + 0x5000000);  // 2M
  bf16_t* W1T   = (bf16_t*)(ws + 0x5200000);  // 8M
  bf16_t* W2T   = (bf16_t*)(ws + 0x5A00000);  // 8M -> 0x6200000

  k_prep<<<3328, 256, 0, stream>>>(value, Wq, Wk, Wv, Qb, Kb, VTb,
                                   Wo, W1, W2, WoT, W1T, W2T);
  k_flash<<<512, 512, 0, stream>>>(Qb, Kb, VTb, AO);
  // Wo-GEMM over (o1+o2): fused instance-sum in A-staging, single K=1024 pass
  k_gemm<5><<<256, 256, 0, stream>>>(AO, WoT, Pg0, nullptr, nullptr,
                                     4096, 1024, 1024, AO + 4194304);
  k_ln<4><<<4096, 256, 0, stream>>>(Pg0, g1, b1, Xf, Xb, nullptr, bo, query);
  // FFN1: 256x128-tile 8-wave GEMM
  k_gemm2<1><<<512, 512, 0, stream>>>(Xb, W1T, Hb, bf1, nullptr, 4096, 4096, 1024);
  // FFN2: 256x128-tile 8-wave GEMM, split-K=2 (grid 256)
  k_gemm2<3><<<256, 512, 0, stream>>>(Hb, W2T, Psk0, nullptr, Psk1, 4096, 1024, 4096);
  k_ln<2><<<4096, 256, 0, stream>>>(Psk0, g3, b3, (float*)d_out, nullptr,
                                    Psk1, bf2, Xf);
}

// Round 26
// 239.189 us; speedup vs baseline: 1.0269x; 1.0269x over previous
//
#include <hip/hip_runtime.h>
#include <hip/hip_bf16.h>

typedef __bf16 bf16_t;
typedef __attribute__((ext_vector_type(8))) __bf16 bf16x8;
typedef __attribute__((ext_vector_type(4))) __bf16 bf16x4;
typedef __attribute__((ext_vector_type(4))) float f32x4;
typedef __attribute__((ext_vector_type(16))) float f32x16;

#define DEV __device__ __forceinline__
#define LOG2E 1.44269504088896f

DEV void gload16(const bf16_t* g, void* l) {
  __builtin_amdgcn_global_load_lds((const __attribute__((address_space(1))) void*)g,
                                   (__attribute__((address_space(3))) void*)l, 16, 0, 0);
}

DEV f32x4 mfma16(bf16x8 a, bf16x8 b, f32x4 c) {
  return __builtin_amdgcn_mfma_f32_16x16x32_bf16(a, b, c, 0, 0, 0);
}
DEV f32x16 mfma32(bf16x8 a, bf16x8 b, f32x16 c) {
  return __builtin_amdgcn_mfma_f32_32x32x16_bf16(a, b, c, 0, 0, 0);
}

// raw v_exp_f32 (2^x) — inputs bounded |x|<~4, no denormal fixup needed
DEV float fexp2(float x) {
#if __has_builtin(__builtin_amdgcn_exp2f)
  return __builtin_amdgcn_exp2f(x);
#else
  float r;
  asm("v_exp_f32 %0, %1" : "=v"(r) : "v"(x));
  return r;
#endif
}

DEV bf16x8 cvt8(const float* p0, const float* p1) {
  bf16x8 v;
  v[0] = (bf16_t)p0[0]; v[1] = (bf16_t)p0[1]; v[2] = (bf16_t)p0[2]; v[3] = (bf16_t)p0[3];
  v[4] = (bf16_t)p1[0]; v[5] = (bf16_t)p1[1]; v[6] = (bf16_t)p1[2]; v[7] = (bf16_t)p1[3];
  return v;
}

DEV unsigned pk2(float lo, float hi) {
  union { bf16_t h[2]; unsigned u; } x;
  x.h[0] = (bf16_t)lo; x.h[1] = (bf16_t)hi;
  return x.u;
}

DEV bf16x8 lds_read_swz7(const bf16_t* base, int row, int kByte) {   // 128B rows, 8-slot swz
  int off = (row << 7) + (kByte ^ ((row & 7) << 4));
  return *(const bf16x8*)((const char*)base + off);
}
DEV bf16x8 lds_read_swz8b(const bf16_t* base, int row, int kByte) {  // 256B rows, 16-slot swz
  int off = (row << 8) + (kByte ^ ((row & 15) << 4));
  return *(const bf16x8*)((const char*)base + off);
}

// ---------------- k_prep: qkv (blocks 0..1023) + weight conversion (1024..3327) ----------------
DEV void wconv_tile(bf16_t* pool, const float* in, bf16_t* out, int R, int C, int tile) {
  bf16_t (*Ts)[72] = (bf16_t(*)[72])pool;  // 64x72
  int tilesC = C >> 6;
  int tr = tile / tilesC, tc = tile % tilesC;
  int t = threadIdx.x;
  int rr = t >> 3, c0 = (t & 7) << 3;
#pragma unroll
  for (int i = 0; i < 2; ++i) {
    int row = rr + i * 32;
    const float* src = in + (size_t)(tr * 64 + row) * C + tc * 64 + c0;
    float4 a = *(const float4*)src;
    float4 b = *(const float4*)(src + 4);
    *(bf16x8*)&Ts[row][c0] = cvt8(&a.x, &b.x);
  }
  __syncthreads();
#pragma unroll
  for (int i = 0; i < 2; ++i) {
    int nl = rr + i * 32;
    bf16x8 v;
#pragma unroll
    for (int j = 0; j < 8; ++j) v[j] = Ts[c0 + j][nl];
    *(bf16x8*)(out + (size_t)(tc * 64 + nl) * R + tr * 64 + c0) = v;
  }
}

DEV void qkv_body(bf16_t* pool, int b, const float* value,
    const float* Wq, const float* Wk, const float* Wv,
    bf16_t* Q, bf16_t* K, bf16_t* VT) {
  bf16_t* Xs = pool;              // 128*72
  bf16_t* Wt = pool + 128 * 72;   // 3 x 64*72
  int cn = b & 15, h = (b >> 4) & 15, n = (b >> 8) & 1, s = b >> 9;
  int t = threadIdx.x, lane = t & 63, w = t >> 6;
  int lg = (lane >> 4) & 3, ll = lane & 15;
  int hbase = (s * 2 + n) * 16 + h;
  const float* xbase = value + (size_t)(((n * 16 + cn) * 2 + s) * 128) * 1024 + h * 64;
#pragma unroll
  for (int i = 0; i < 4; ++i) {
    int c = t + i * 256;
    int row = c >> 3, d0 = (c & 7) << 3;
    const float* src = xbase + (size_t)row * 1024 + d0;
    float4 a = *(const float4*)src;
    float4 b2 = *(const float4*)(src + 4);
    *(bf16x8*)&Xs[row * 72 + d0] = cvt8(&a.x, &b2.x);
  }
  const float* Wm[3] = {Wq, Wk, Wv};
#pragma unroll
  for (int m = 0; m < 3; ++m) {
    float sc = (m == 0) ? (0.03125f * LOG2E) : 1.0f;
    for (int i = 0; i < 16; ++i) {
      int f = t * 16 + i;
      int k = f >> 6, col = f & 63;
      Wt[m * 64 * 72 + col * 72 + k] = (bf16_t)(Wm[m][f] * sc);
    }
  }
  __syncthreads();
  f32x4 acc[3][2][4] = {};
#pragma unroll
  for (int kc = 0; kc < 2; ++kc) {
    bf16x8 a[2];
#pragma unroll
    for (int rt = 0; rt < 2; ++rt)
      a[rt] = *(const bf16x8*)&Xs[(w * 32 + rt * 16 + ll) * 72 + kc * 32 + lg * 8];
#pragma unroll
    for (int m = 0; m < 3; ++m)
#pragma unroll
      for (int ct = 0; ct < 4; ++ct) {
        bf16x8 bf = *(const bf16x8*)&Wt[m * 64 * 72 + (ct * 16 + ll) * 72 + kc * 32 + lg * 8];
#pragma unroll
        for (int rt = 0; rt < 2; ++rt)
          acc[m][rt][ct] = mfma16(a[rt], bf, acc[m][rt][ct]);
      }
  }
  bf16_t* outp[2] = {Q, K};
  size_t obase = ((size_t)hbase * 2048 + cn * 128) * 64;
#pragma unroll
  for (int m = 0; m < 2; ++m)
#pragma unroll
    for (int rt = 0; rt < 2; ++rt)
#pragma unroll
      for (int ct = 0; ct < 4; ++ct)
#pragma unroll
        for (int r = 0; r < 4; ++r) {
          int lrow = w * 32 + rt * 16 + lg * 4 + r;
          int d = ct * 16 + ll;
          outp[m][obase + (size_t)lrow * 64 + d] = (bf16_t)acc[m][rt][ct][r];
        }
  __syncthreads();
  bf16_t* XsT = Xs;  // [64][136]
#pragma unroll
  for (int rt = 0; rt < 2; ++rt)
#pragma unroll
    for (int ct = 0; ct < 4; ++ct)
#pragma unroll
      for (int r = 0; r < 4; ++r) {
        int lrow = w * 32 + rt * 16 + lg * 4 + r;
        int d = ct * 16 + ll;
        XsT[d * 136 + lrow] = (bf16_t)acc[2][rt][ct][r];
      }
  __syncthreads();
#pragma unroll
  for (int p = 0; p < 4; ++p) {
    int d = p * 16 + (t >> 4);
    int l0 = (t & 15) * 8;
    bf16x8 v;
#pragma unroll
    for (int j = 0; j < 8; ++j) {
      int pos = l0 + j;
      int key = (pos & ~12) | ((pos & 4) << 1) | ((pos & 8) >> 1);  // swap bits 2,3
      v[j] = XsT[d * 136 + key];
    }
    *(bf16x8*)(VT + ((size_t)hbase * 64 + d) * 2048 + cn * 128 + l0) = v;
  }
}

__global__ __launch_bounds__(256) void k_prep(const float* __restrict__ value,
    const float* __restrict__ Wq, const float* __restrict__ Wk, const float* __restrict__ Wv,
    bf16_t* __restrict__ Q, bf16_t* __restrict__ K, bf16_t* __restrict__ VT,
    const float* __restrict__ Wo, const float* __restrict__ W1, const float* __restrict__ W2,
    bf16_t* __restrict__ WoT, bf16_t* __restrict__ W1T, bf16_t* __restrict__ W2T) {
  __shared__ alignas(16) bf16_t pool[128 * 72 + 3 * 64 * 72];  // 45 KB
  int b = blockIdx.x;
  if (b < 1024) {
    qkv_body(pool, b, value, Wq, Wk, Wv, Q, K, VT);
  } else {
    int tile = b - 1024;
    if (tile < 256) wconv_tile(pool, Wo, WoT, 1024, 1024, tile);
    else if (tile < 1280) wconv_tile(pool, W1, W1T, 1024, 4096, tile - 256);
    else wconv_tile(pool, W2, W2T, 4096, 1024, tile - 1280);
  }
}

// ---------------- flash attention (r22 proven: 8-wave, launch_bounds(512,2)) ----------------
__global__ __launch_bounds__(512, 2) void k_flash(const bf16_t* __restrict__ Qg,
    const bf16_t* __restrict__ Kg, const bf16_t* __restrict__ VTg, bf16_t* __restrict__ AO) {
  __shared__ alignas(16) bf16_t Ks[2][128 * 64];
  __shared__ alignas(16) bf16_t Vt[2][64 * 128];
  int b0 = blockIdx.x;
  int b = (b0 & 7) * 64 + (b0 >> 3);  // T1 chunked XCD swizzle (nwg=512)
  int qt = b & 7, h = (b >> 3) & 15, n = (b >> 7) & 1, s = b >> 8;
  int t = threadIdx.x, lane = t & 63, w = t >> 6;  // w in 0..7
  int l31 = lane & 31, hi = lane >> 5;
  size_t hoff = ((size_t)((s * 2 + n) * 16 + h)) << 17;
  const bf16_t* Qh = Qg + hoff;
  const bf16_t* Kh = Kg + hoff;
  const bf16_t* VTh = VTg + hoff;
  int qrow = qt * 256 + w * 32 + l31;
  bf16x8 qf[4];
#pragma unroll
  for (int kc4 = 0; kc4 < 4; ++kc4)
    qf[kc4] = *(const bf16x8*)(Qh + (size_t)qrow * 64 + kc4 * 16 + hi * 8);
  f32x16 oacc[2], lacc, zro;
#pragma unroll
  for (int r = 0; r < 16; ++r) {
    oacc[0][r] = 0.f; oacc[1][r] = 0.f; lacc[r] = 0.f; zro[r] = 0.f;
  }
  bf16x8 ones;
#pragma unroll
  for (int j = 0; j < 8; ++j) ones[j] = (bf16_t)1.0f;

  int l8s = (((lane & 7) ^ (lane >> 3)) << 3);
  const bf16_t* kbase = Kh + (size_t)(w * 16 + (lane >> 3)) * 64 + l8s;
  const bf16_t* vbase[2];
#pragma unroll
  for (int i = 0; i < 2; ++i) {
    int row = w * 8 + i * 4 + (lane >> 4);
    vbase[i] = VTh + (size_t)row * 2048 + (((lane & 15) ^ (row & 15)) << 3);
  }
  auto stage = [&](int buf, int kt0) {
    int koff = kt0 * 8192;
    int voff = kt0 * 128;
#pragma unroll
    for (int i = 0; i < 2; ++i)
      gload16(kbase + koff + i * 512, (char*)Ks[buf] + (w * 2 + i) * 1024);
#pragma unroll
    for (int i = 0; i < 2; ++i)
      gload16(vbase[i] + voff, (char*)Vt[buf] + (w * 2 + i) * 1024);
  };

  stage(0, 0);
  __syncthreads();
  for (int kt0 = 0; kt0 < 16; ++kt0) {
    int cur = kt0 & 1;
    if (kt0 < 15) stage(cur ^ 1, kt0 + 1);
    f32x16 sacc[4];
    __builtin_amdgcn_s_setprio(1);
#pragma unroll
    for (int kb = 0; kb < 4; ++kb) {
      bf16x8 kf = lds_read_swz7(Ks[cur], kb * 32 + l31, hi * 16);
      sacc[kb] = mfma32(kf, qf[0], zro);
#pragma unroll
      for (int kc4 = 1; kc4 < 4; ++kc4) {
        kf = lds_read_swz7(Ks[cur], kb * 32 + l31, kc4 * 32 + hi * 16);
        sacc[kb] = mfma32(kf, qf[kc4], sacc[kb]);
      }
    }
    __builtin_amdgcn_s_setprio(0);
#pragma unroll
    for (int kb = 0; kb < 4; ++kb) {
#pragma unroll
      for (int r = 0; r < 16; ++r)
        sacc[kb][r] = fexp2(sacc[kb][r]);
      __builtin_amdgcn_s_setprio(1);
#pragma unroll
      for (int c = 0; c < 2; ++c) {
        int base = 8 * c;
        union { unsigned u[4]; bf16x8 v; } pb;
#pragma unroll
        for (int jj = 0; jj < 4; ++jj)
          pb.u[jj] = pk2(sacc[kb][base + 2 * jj], sacc[kb][base + 2 * jj + 1]);
        int kc16 = kb * 2 + c;
        lacc = mfma32(ones, pb.v, lacc);
#pragma unroll
        for (int dblk = 0; dblk < 2; ++dblk) {
          bf16x8 vf = lds_read_swz8b(Vt[cur], dblk * 32 + l31, kc16 * 32 + hi * 16);
          oacc[dblk] = mfma32(vf, pb.v, oacc[dblk]);
        }
      }
      __builtin_amdgcn_s_setprio(0);
    }
    __syncthreads();
  }
  float lrun = lacc[0];
  bf16_t* AOs = AO + ((size_t)s) * 4194304;
  float rl = 1.f / lrun;
  size_t rowbase = ((size_t)(n * 2048 + qrow)) * 1024 + h * 64;
#pragma unroll
  for (int dblk = 0; dblk < 2; ++dblk)
#pragma unroll
    for (int rp = 0; rp < 4; ++rp) {
      bf16x4 ov;
#pragma unroll
      for (int rq = 0; rq < 4; ++rq) ov[rq] = (bf16_t)(oacc[dblk][rp * 4 + rq] * rl);
      int d0 = dblk * 32 + rp * 8 + hi * 4;
      *(bf16x4*)(AOs + rowbase + d0) = ov;
    }
}

// ---------------- GEMM 128x128 (4-wave) ----------------
// EPI 3: split-K raw partials (ks=0->outp, ks=1->add); EPI 5: fused instance-sum, f32 out
template <int EPI>
__global__ __launch_bounds__(256) void k_gemm(const bf16_t* __restrict__ A,
    const bf16_t* __restrict__ BT, void* __restrict__ outp,
    const float* __restrict__ bias, const void* __restrict__ add,
    int M, int N, int K, const bf16_t* __restrict__ A2) {
  __shared__ alignas(16) bf16_t As[128 * 64];
  __shared__ alignas(16) bf16_t Bs[128 * 64];
  int ntn = N >> 7;
  int nwg = gridDim.x;
  int b0 = blockIdx.x;
  int cpx = nwg >> 3;
  int b = (b0 & 7) * cpx + (b0 >> 3);  // chunked XCD swizzle (nwg % 8 == 0)
  int ks = 0, k0 = 0, kend = K;
  if (EPI == 3) {
    int half = nwg >> 1;
    ks = (b >= half) ? 1 : 0;
    b -= ks * half;
    int kh = K >> 1;
    k0 = ks * kh;
    kend = k0 + kh;
  }
  int bm = b / ntn, bn = b % ntn;
  int t = threadIdx.x, lane = t & 63, w = t >> 6;
  int wr = w >> 1, wc = w & 1;
  int lg = (lane >> 4) & 3, ll = lane & 15;
  f32x4 acc[4][4] = {};
  int rA = bm * 128, rB = bn * 128;
  int l8s = (((lane & 7) ^ (lane >> 3)) << 3);
  for (int kt = k0; kt < kend; kt += 64) {
#pragma unroll
    for (int i = 0; i < 4; ++i) {
      int kb = w * 4 + i;
      int row = kb * 8 + (lane >> 3);
      size_t off = (size_t)(rA + row) * K + kt + l8s;
      if (EPI == 5) {
        bf16x8 a1 = *(const bf16x8*)(A + off);
        bf16x8 a2 = *(const bf16x8*)(A2 + off);
        bf16x8 sv;
#pragma unroll
        for (int j = 0; j < 8; ++j) sv[j] = (bf16_t)((float)a1[j] + (float)a2[j]);
        *(bf16x8*)((char*)As + kb * 1024 + lane * 16) = sv;
      } else {
        gload16(A + off, (char*)As + kb * 1024);
      }
      gload16(BT + (size_t)(rB + row) * K + kt + l8s, (char*)Bs + kb * 1024);
    }
    __syncthreads();
#pragma unroll
    for (int kc = 0; kc < 2; ++kc) {
      bf16x8 a[4], bb[4];
#pragma unroll
      for (int m = 0; m < 4; ++m)
        a[m] = lds_read_swz7(As, wr * 64 + m * 16 + ll, kc * 64 + lg * 16);
#pragma unroll
      for (int nn = 0; nn < 4; ++nn)
        bb[nn] = lds_read_swz7(Bs, wc * 64 + nn * 16 + ll, kc * 64 + lg * 16);
#pragma unroll
      for (int m = 0; m < 4; ++m)
#pragma unroll
        for (int nn = 0; nn < 4; ++nn)
          acc[m][nn] = mfma16(a[m], bb[nn], acc[m][nn]);
    }
    __syncthreads();
  }
#pragma unroll
  for (int m = 0; m < 4; ++m)
#pragma unroll
    for (int nn = 0; nn < 4; ++nn)
#pragma unroll
      for (int r = 0; r < 4; ++r) {
        int row = bm * 128 + wr * 64 + m * 16 + lg * 4 + r;
        int col = bn * 128 + wc * 64 + nn * 16 + ll;
        float v = acc[m][nn][r];
        size_t idx = (size_t)row * N + col;
        float* dst = (EPI == 3 && ks) ? (float*)add : (float*)outp;
        dst[idx] = v;
      }
}

// ---------------- GEMM 256x128 (8-wave, launch_bounds(512,2)): relu(acc+bias) bf16 out ----
__global__ __launch_bounds__(512, 2) void k_gemm2(const bf16_t* __restrict__ A,
    const bf16_t* __restrict__ BT, bf16_t* __restrict__ outp,
    const float* __restrict__ bias, int M, int N, int K) {
  __shared__ alignas(16) bf16_t As[256 * 64];  // 32 KB, 32 chunks
  __shared__ alignas(16) bf16_t Bs[128 * 64];  // 16 KB, 16 chunks
  int ntn = N >> 7;
  int nwg = gridDim.x;
  int b0 = blockIdx.x;
  int cpx = nwg >> 3;
  int b = (b0 & 7) * cpx + (b0 >> 3);  // chunked XCD swizzle
  int bm = b / ntn, bn = b % ntn;
  int t = threadIdx.x, lane = t & 63, w = t >> 6;  // w in 0..7
  int wr = w >> 1, wc = w & 1;                      // 4x2 wave grid
  int lg = (lane >> 4) & 3, ll = lane & 15;
  f32x4 acc[4][4] = {};
  int rA = bm * 256, rB = bn * 128;
  int l8s = (((lane & 7) ^ (lane >> 3)) << 3);
  for (int kt = 0; kt < K; kt += 64) {
#pragma unroll
    for (int i = 0; i < 4; ++i) {  // A: 32 chunks, 4 per wave
      int kb = w * 4 + i;
      int row = kb * 8 + (lane >> 3);
      gload16(A + (size_t)(rA + row) * K + kt + l8s, (char*)As + kb * 1024);
    }
#pragma unroll
    for (int i = 0; i < 2; ++i) {  // B: 16 chunks, 2 per wave
      int kb = w * 2 + i;
      int row = kb * 8 + (lane >> 3);
      gload16(BT + (size_t)(rB + row) * K + kt + l8s, (char*)Bs + kb * 1024);
    }
    __syncthreads();
#pragma unroll
    for (int kc = 0; kc < 2; ++kc) {
      bf16x8 a[4], bb[4];
#pragma unroll
      for (int m = 0; m < 4; ++m)
        a[m] = lds_read_swz7(As, wr * 64 + m * 16 + ll, kc * 64 + lg * 16);
#pragma unroll
      for (int nn = 0; nn < 4; ++nn)
        bb[nn] = lds_read_swz7(Bs, wc * 64 + nn * 16 + ll, kc * 64 + lg * 16);
#pragma unroll
      for (int m = 0; m < 4; ++m)
#pragma unroll
        for (int nn = 0; nn < 4; ++nn)
          acc[m][nn] = mfma16(a[m], bb[nn], acc[m][nn]);
    }
    __syncthreads();
  }
#pragma unroll
  for (int m = 0; m < 4; ++m)
#pragma unroll
    for (int nn = 0; nn < 4; ++nn)
#pragma unroll
      for (int r = 0; r < 4; ++r) {
        int row = bm * 256 + wr * 64 + m * 16 + lg * 4 + r;
        int col = bn * 128 + wc * 64 + nn * 16 + ll;
        float v = acc[m][nn][r] + bias[col];
        outp[(size_t)row * N + col] = (bf16_t)fmaxf(v, 0.f);
      }
}

// ---------------- LayerNorm over 1024 cols ----------------
// MODE 2: v = T+T2+bias2+add2, write xf only (final f32 out)
// MODE 4: v = T+2*bias2+add2, write xf + xb (post-attention LN, single partial)
template <int MODE>
__global__ __launch_bounds__(256) void k_ln(const float* __restrict__ T,
    const float* __restrict__ g, const float* __restrict__ b,
    float* __restrict__ xf, bf16_t* __restrict__ xb,
    const float* __restrict__ T2, const float* __restrict__ bias2,
    const float* __restrict__ add2) {
  int row = blockIdx.x, t = threadIdx.x;
  float4 v = ((const float4*)(T + (size_t)row * 1024))[t];
  {
    const float4 vb = ((const float4*)bias2)[t];
    const float4 va = ((const float4*)(add2 + (size_t)row * 1024))[t];
    float bs = (MODE == 4) ? 2.f : 1.f;
    if (MODE != 4) {
      const float4 v2 = ((const float4*)(T2 + (size_t)row * 1024))[t];
      v.x += v2.x; v.y += v2.y; v.z += v2.z; v.w += v2.w;
    }
    v.x += bs * vb.x + va.x;
    v.y += bs * vb.y + va.y;
    v.z += bs * vb.z + va.z;
    v.w += bs * vb.w + va.w;
  }
  float s1 = v.x + v.y + v.z + v.w;
  float s2 = v.x * v.x + v.y * v.y + v.z * v.z + v.w * v.w;
#pragma unroll
  for (int off = 1; off < 64; off <<= 1) {
    s1 += __shfl_xor(s1, off);
    s2 += __shfl_xor(s2, off);
  }
  __shared__ float red[8];
  int w = t >> 6, lane = t & 63;
  if (lane == 0) { red[w] = s1; red[w + 4] = s2; }
  __syncthreads();
  s1 = red[0] + red[1] + red[2] + red[3];
  s2 = red[4] + red[5] + red[6] + red[7];
  float mean = s1 * (1.f / 1024.f);
  float var = s2 * (1.f / 1024.f) - mean * mean;
  float rstd = rsqrtf(var + 1e-5f);
  const float4 gv = ((const float4*)g)[t];
  const float4 bv = ((const float4*)b)[t];
  float4 o;
  o.x = (v.x - mean) * rstd * gv.x + bv.x;
  o.y = (v.y - mean) * rstd * gv.y + bv.y;
  o.z = (v.z - mean) * rstd * gv.z + bv.z;
  o.w = (v.w - mean) * rstd * gv.w + bv.w;
  ((float4*)(xf + (size_t)row * 1024))[t] = o;
  if (MODE == 4) {
    bf16x4 ob;
    ob[0] = (bf16_t)o.x; ob[1] = (bf16_t)o.y; ob[2] = (bf16_t)o.z; ob[3] = (bf16_t)o.w;
    *(bf16x4*)(xb + (size_t)row * 1024 + t * 4) = ob;
  }
}

extern "C" void kernel_launch(void* const* d_in, const int* in_sizes, int n_in,
                              void* d_out, int out_size, void* d_ws, size_t ws_size,
                              hipStream_t stream) {
  const float* value = (const float*)d_in[0];
  const float* query = (const float*)d_in[2];
  const float* Wv = (const float*)d_in[5];
  const float* Wk = (const float*)d_in[6];
  const float* Wq = (const float*)d_in[7];
  const float* Wo = (const float*)d_in[8];
  const float* bo = (const float*)d_in[9];
  const float* g1 = (const float*)d_in[10];
  const float* b1 = (const float*)d_in[11];
  const float* W1 = (const float*)d_in[12];
  const float* bf1 = (const float*)d_in[13];
  const float* W2 = (const float*)d_in[14];
  const float* bf2 = (const float*)d_in[15];
  const float* g3 = (const float*)d_in[16];
  const float* b3 = (const float*)d_in[17];

  char* ws = (char*)d_ws;
  // race-free lifetime-planned layout, peak 0x6200000 = 98 MiB
  bf16_t* Qb    = (bf16_t*)(ws + 0x0000000);  // 16M, dead after flash
  bf16_t* Kb    = (bf16_t*)(ws + 0x1000000);  // 16M, dead after flash
  bf16_t* VTb   = (bf16_t*)(ws + 0x2000000);  // 16M, dead after flash
  bf16_t* AO    = (bf16_t*)(ws + 0x3000000);  // 16M (2x8M), dead after gemmWo
  float*  Pg0   = (float*) (ws + 0x0000000);  // 16M (over dead Qb), dead after ln4
  float*  Xf    = (float*) (ws + 0x2000000);  // 16M (over dead VTb), live to end
  bf16_t* Xb    = (bf16_t*)(ws + 0x4000000);  // 8M  (fresh), dead after gemm1
  bf16_t* Hb    = (bf16_t*)(ws + 0x0000000);  // 32M (over dead Pg0 + Kb), dead after gemmFFN2
  float*  Psk0  = (float*) (ws + 0x3000000);  // 16M (over dead AO)
  float*  Psk1  = (float*) (ws + 0x4000000);  // 16M (over dead Xb)
  bf16_t* WoT   = (bf16_t*)(ws + 0x5000000);  // 2M
  bf16_t* W1T   = (bf16_t*)(ws + 0x5200000);  // 8M
  bf16_t* W2T   = (bf16_t*)(ws + 0x5A00000);  // 8M -> 0x6200000

  k_prep<<<3328, 256, 0, stream>>>(value, Wq, Wk, Wv, Qb, Kb, VTb,
                                   Wo, W1, W2, WoT, W1T, W2T);
  k_flash<<<512, 512, 0, stream>>>(Qb, Kb, VTb, AO);
  // Wo-GEMM over (o1+o2): fused instance-sum in A-staging, single K=1024 pass
  k_gemm<5><<<256, 256, 0, stream>>>(AO, WoT, Pg0, nullptr, nullptr,
                                     4096, 1024, 1024, AO + 4194304);
  k_ln<4><<<4096, 256, 0, stream>>>(Pg0, g1, b1, Xf, Xb, nullptr, bo, query);
  // FFN1: 256x128-tile 8-wave GEMM (r24-proven)
  k_gemm2<<<512, 512, 0, stream>>>(Xb, W1T, Hb, bf1, 4096, 4096, 1024);
  // FFN2: 128x128-tile 4-wave split-K=2 (r24-proven: 512 blocks = 2 blocks/CU)
  k_gemm<3><<<512, 256, 0, stream>>>(Hb, W2T, Psk0, nullptr, Psk1, 4096, 1024, 4096, nullptr);
  k_ln<2><<<4096, 256, 0, stream>>>(Psk0, g3, b3, (float*)d_out, nullptr,
                                    Psk1, bf2, Xf);
}